// Round 4
// baseline (381.151 us; speedup 1.0000x reference)
//
#include <hip/hip_runtime.h>
#include <hip/hip_bf16.h>

typedef __attribute__((ext_vector_type(8))) short bf16x8;
typedef __attribute__((ext_vector_type(4))) float f32x4;

#define N_NODES 200000
#define N_STRIPS (N_NODES / 16)      // 12500
#define N_TRIP  600000
#define NPAIRS  (N_TRIP / 32)        // 18750
#define PI_F 3.14159265358979f
#define S1_RS 264                    // stage1 LDS row stride (shorts)

__device__ __forceinline__ unsigned short f2bf(float f) {
    unsigned int u = __float_as_uint(f);
    unsigned int r = u + 0x7FFFu + ((u >> 16) & 1u);   // RNE
    return (unsigned short)(r >> 16);
}
__device__ __forceinline__ float bf2f(unsigned short u) {
    return __uint_as_float(((unsigned int)u) << 16);
}
__device__ __forceinline__ float elu(float x) {
    return (x > 0.f) ? x : (__expf(x) - 1.f);
}
__device__ __forceinline__ unsigned int f2bf2(float x, float y) {
    union { __hip_bfloat162 b; unsigned int u; } cv;
    cv.b = __float22bfloat162_rn(make_float2(x, y));   // v_cvt_pk_bf16_f32
    return cv.u;                                        // low16=x, high16=y
}

// ---------------------------------------------------------------------------
// prep: W0 [768][64] fp32 -> w0t2 bf16 fragment-ordered
// ---------------------------------------------------------------------------
__global__ void prep_w0(const float* __restrict__ W0, unsigned short* __restrict__ w0t2) {
    int g = blockIdx.x * 256 + threadIdx.x;      // 0 .. 49151
    int j    = g & 31;
    int tt   = (g >> 5) & 15;
    int rest = g >> 9;
    int nt = rest % 12;
    int kc = rest / 12;
    int n = nt * 16 + tt;
    int s = n >> 6;
    int o = n & 63;
    w0t2[g] = f2bf(W0[(s * 256 + kc * 32 + j) * 64 + o]);
}

// ---------------------------------------------------------------------------
// stage1: P[node][192] = bf16(h @ W0' + b0/3 per segment)
// B register-resident; A double-buffered through LDS.
// ---------------------------------------------------------------------------
__global__ __launch_bounds__(256, 2) void stage1(const float* __restrict__ h,
                                                 const unsigned short* __restrict__ w0t2,
                                                 const float* __restrict__ b0,
                                                 unsigned short* __restrict__ P) {
    __shared__ unsigned short A[2][16 * S1_RS];
    int tid = threadIdx.x;
    int lane = tid & 63, wid = tid >> 6;
    int t = lane & 15, q = lane >> 4;

    bf16x8 Bf[8][3];
#pragma unroll
    for (int kc = 0; kc < 8; ++kc)
#pragma unroll
        for (int i = 0; i < 3; ++i)
            Bf[kc][i] = *(const bf16x8*)(w0t2 + (size_t)((kc * 12 + wid * 3 + i) * 16 + t) * 32 + q * 8);

    float b0v[3];
#pragma unroll
    for (int i = 0; i < 3; ++i) b0v[i] = b0[(wid * 3 + i) * 16 + t] * (1.f / 3.f);

    int s = blockIdx.x;
    float4 R[4];
    {
        const float4* src = (const float4*)(h + (size_t)s * 4096);
#pragma unroll
        for (int p4 = 0; p4 < 4; ++p4) R[p4] = src[p4 * 256 + tid];
    }
    int buf = 0;
    while (s < N_STRIPS) {
#pragma unroll
        for (int p4 = 0; p4 < 4; ++p4) {
            uint2 pk;
            pk.x = f2bf2(R[p4].x, R[p4].y);
            pk.y = f2bf2(R[p4].z, R[p4].w);
            *(uint2*)&A[buf][(p4 * 4 + wid) * S1_RS + lane * 4] = pk;
        }
        __syncthreads();
        int snext = s + gridDim.x;
        if (snext < N_STRIPS) {
            const float4* src = (const float4*)(h + (size_t)snext * 4096);
#pragma unroll
            for (int p4 = 0; p4 < 4; ++p4) R[p4] = src[p4 * 256 + tid];
        }
        const unsigned short* ab = &A[buf][t * S1_RS + q * 8];
        bf16x8 af[8];
#pragma unroll
        for (int kc = 0; kc < 8; ++kc) af[kc] = *(const bf16x8*)(ab + kc * 32);

        f32x4 acc[3];
#pragma unroll
        for (int i = 0; i < 3; ++i) acc[i] = (f32x4){0.f, 0.f, 0.f, 0.f};
#pragma unroll
        for (int kc = 0; kc < 8; ++kc) {
            acc[0] = __builtin_amdgcn_mfma_f32_16x16x32_bf16(af[kc], Bf[kc][0], acc[0], 0, 0, 0);
            acc[1] = __builtin_amdgcn_mfma_f32_16x16x32_bf16(af[kc], Bf[kc][1], acc[1], 0, 0, 0);
            acc[2] = __builtin_amdgcn_mfma_f32_16x16x32_bf16(af[kc], Bf[kc][2], acc[2], 0, 0, 0);
        }
#pragma unroll
        for (int i = 0; i < 3; ++i)
#pragma unroll
            for (int r = 0; r < 4; ++r)
                P[(size_t)(s * 16 + q * 4 + r) * 192 + (wid * 3 + i) * 16 + t] = f2bf(acc[i][r] + b0v[i]);
        s = snext;
        buf ^= 1;
    }
}

// ---------------------------------------------------------------------------
// stage2: per-triplet MLP, dual-tile per wave. fr is reloaded in-place right
// after buildZ consumes it (prefetch distance ~1 iter, no frn copy -> peak
// VGPR ~220, 2 waves/SIMD). Wt reads batched in pairs of mt (32 VGPR).
// ---------------------------------------------------------------------------
struct I3 { int a, b, c; };

__global__ __launch_bounds__(256, 2) void stage2(
    const unsigned short* __restrict__ P, const int* __restrict__ idxs,
    const float* __restrict__ Ws, const float* __restrict__ bs,
    const float* __restrict__ W1, const float* __restrict__ b1,
    const float* __restrict__ W2, const float* __restrict__ b2,
    const float* __restrict__ W3, const float* __restrict__ b3,
    const float* __restrict__ W4, const float* __restrict__ b4,
    float* __restrict__ out)
{
    __shared__ unsigned short Wt[4][64][72];     // W^T bf16 [layer][m][k]
    __shared__ float bC[3][64];                  // 0:b1  1:bs+b2  2:b3
    __shared__ float W4S[128];
    __shared__ float b4S[2];
    __shared__ unsigned short zb[4][2][16][72];  // per-wave transform buf

    int tid = threadIdx.x;
    {
        const float* wsrc[4] = {Ws, W1, W2, W3};
#pragma unroll
        for (int l = 0; l < 4; ++l)
            for (int i = 0; i < 16; ++i) {
                int e = i * 256 + tid;
                int k = e >> 6, m = e & 63;
                Wt[l][m][k] = f2bf(wsrc[l][e]);
            }
        if (tid < 64) {
            bC[0][tid] = b1[tid];
            bC[1][tid] = bs[tid] + b2[tid];
            bC[2][tid] = b3[tid];
        }
        if (tid < 128) W4S[tid] = W4[tid];
        if (tid < 2)   b4S[tid] = b4[tid];
    }
    __syncthreads();

    int lane = tid & 63, wid = tid >> 6;
    int t = lane & 15, q = lane >> 4;

    unsigned short* zbase = &zb[wid][0][0][0];
    unsigned short* zwA = zbase + t * 72 + 4 * q;
    const unsigned short* zrA = zbase + t * 72 + 8 * q;
    unsigned short* zwB = zwA + 16 * 72;
    const unsigned short* zrB = zrA + 16 * 72;

    auto loadIdx = [&](int p, I3& A, I3& B) {
        int tripA = p * 32 + t;
        A.a = idxs[tripA * 3 + 0]; A.b = idxs[tripA * 3 + 1]; A.c = idxs[tripA * 3 + 2];
        int tripB = tripA + 16;
        B.a = idxs[tripB * 3 + 0]; B.b = idxs[tripB * 3 + 1]; B.c = idxs[tripB * 3 + 2];
    };
    auto loadFrags = [&](const I3& iA, const I3& iB, bf16x8* fr) {
        const unsigned short* a0 = P + (size_t)iA.a * 192 + 8 * q;
        const unsigned short* a1 = P + (size_t)iA.b * 192 + 64 + 8 * q;
        const unsigned short* a2 = P + (size_t)iA.c * 192 + 128 + 8 * q;
        fr[0] = *(const bf16x8*)(a0);  fr[1] = *(const bf16x8*)(a0 + 32);
        fr[2] = *(const bf16x8*)(a1);  fr[3] = *(const bf16x8*)(a1 + 32);
        fr[4] = *(const bf16x8*)(a2);  fr[5] = *(const bf16x8*)(a2 + 32);
        const unsigned short* c0 = P + (size_t)iB.a * 192 + 8 * q;
        const unsigned short* c1 = P + (size_t)iB.b * 192 + 64 + 8 * q;
        const unsigned short* c2 = P + (size_t)iB.c * 192 + 128 + 8 * q;
        fr[6] = *(const bf16x8*)(c0);  fr[7] = *(const bf16x8*)(c0 + 32);
        fr[8] = *(const bf16x8*)(c1);  fr[9] = *(const bf16x8*)(c1 + 32);
        fr[10] = *(const bf16x8*)(c2); fr[11] = *(const bf16x8*)(c2 + 32);
    };
    auto buildZ = [&](const bf16x8* fr, bf16x8* z) {
#pragma unroll
        for (int c = 0; c < 2; ++c) {
            bf16x8 v0 = fr[0 + c], v1 = fr[2 + c], v2 = fr[4 + c];
            float x[8];
#pragma unroll
            for (int j = 0; j < 8; ++j)
                x[j] = elu(bf2f((unsigned short)v0[j]) + bf2f((unsigned short)v1[j])
                         + bf2f((unsigned short)v2[j]));
            union { bf16x8 v; uint4 u; } pk;
            pk.u.x = f2bf2(x[0], x[1]); pk.u.y = f2bf2(x[2], x[3]);
            pk.u.z = f2bf2(x[4], x[5]); pk.u.w = f2bf2(x[6], x[7]);
            z[c] = pk.v;
        }
    };
    // dual GEMM: Wt frag reads batched per pair of mt (32 VGPR transient)
    auto gemmDual = [&](int L, const bf16x8* zA, const bf16x8* zB2, f32x4* aA, f32x4* aB) {
#pragma unroll
        for (int mtp = 0; mtp < 2; ++mtp) {
            bf16x8 wa0 = *(const bf16x8*)&Wt[L][(mtp * 2 + 0) * 16 + t][q * 8];
            bf16x8 wb0 = *(const bf16x8*)&Wt[L][(mtp * 2 + 0) * 16 + t][32 + q * 8];
            bf16x8 wa1 = *(const bf16x8*)&Wt[L][(mtp * 2 + 1) * 16 + t][q * 8];
            bf16x8 wb1 = *(const bf16x8*)&Wt[L][(mtp * 2 + 1) * 16 + t][32 + q * 8];
            f32x4 x0 = (f32x4){0.f, 0.f, 0.f, 0.f};
            x0 = __builtin_amdgcn_mfma_f32_16x16x32_bf16(wa0, zA[0], x0, 0, 0, 0);
            x0 = __builtin_amdgcn_mfma_f32_16x16x32_bf16(wb0, zA[1], x0, 0, 0, 0);
            aA[mtp * 2 + 0] = x0;
            f32x4 y0 = (f32x4){0.f, 0.f, 0.f, 0.f};
            y0 = __builtin_amdgcn_mfma_f32_16x16x32_bf16(wa0, zB2[0], y0, 0, 0, 0);
            y0 = __builtin_amdgcn_mfma_f32_16x16x32_bf16(wb0, zB2[1], y0, 0, 0, 0);
            aB[mtp * 2 + 0] = y0;
            f32x4 x1 = (f32x4){0.f, 0.f, 0.f, 0.f};
            x1 = __builtin_amdgcn_mfma_f32_16x16x32_bf16(wa1, zA[0], x1, 0, 0, 0);
            x1 = __builtin_amdgcn_mfma_f32_16x16x32_bf16(wb1, zA[1], x1, 0, 0, 0);
            aA[mtp * 2 + 1] = x1;
            f32x4 y1 = (f32x4){0.f, 0.f, 0.f, 0.f};
            y1 = __builtin_amdgcn_mfma_f32_16x16x32_bf16(wa1, zB2[0], y1, 0, 0, 0);
            y1 = __builtin_amdgcn_mfma_f32_16x16x32_bf16(wb1, zB2[1], y1, 0, 0, 0);
            aB[mtp * 2 + 1] = y1;
        }
    };
    auto c2bDual = [&](f32x4* actA, f32x4* actB, bf16x8* oA, bf16x8* oB) {
#pragma unroll
        for (int mt = 0; mt < 4; ++mt) {
            uint2 pa, pb;
            pa.x = f2bf2(actA[mt][0], actA[mt][1]); pa.y = f2bf2(actA[mt][2], actA[mt][3]);
            pb.x = f2bf2(actB[mt][0], actB[mt][1]); pb.y = f2bf2(actB[mt][2], actB[mt][3]);
            *(uint2*)(zwA + mt * 16) = pa;
            *(uint2*)(zwB + mt * 16) = pb;
        }
        asm volatile("s_waitcnt lgkmcnt(0)" ::: "memory");
        oA[0] = *(const bf16x8*)(zrA); oA[1] = *(const bf16x8*)(zrA + 32);
        oB[0] = *(const bf16x8*)(zrB); oB[1] = *(const bf16x8*)(zrB + 32);
    };
    auto epi = [&](f32x4* ta, int trip) {
        float pp0 = 0.f, pp1 = 0.f;
#pragma unroll
        for (int mt = 0; mt < 4; ++mt) {
            float4 bv  = *(const float4*)&bC[2][mt * 16 + 4 * q];
            float4 w4a = *(const float4*)&W4S[(mt * 16 + 4 * q) * 2];
            float4 w4b = *(const float4*)&W4S[(mt * 16 + 4 * q) * 2 + 4];
#pragma unroll
            for (int r = 0; r < 4; ++r) {
                float x = elu(ta[mt][r] + ((const float*)&bv)[r]);
                float w40 = (r == 0) ? w4a.x : (r == 1) ? w4a.z : (r == 2) ? w4b.x : w4b.z;
                float w41 = (r == 0) ? w4a.y : (r == 1) ? w4a.w : (r == 2) ? w4b.y : w4b.w;
                pp0 += x * w40;
                pp1 += x * w41;
            }
        }
        pp0 += __shfl_xor(pp0, 16); pp0 += __shfl_xor(pp0, 32);
        pp1 += __shfl_xor(pp1, 16); pp1 += __shfl_xor(pp1, 32);
        if (q == 0) {
            float c0 = pp0 + b4S[0];
            float c1 = pp1 + b4S[1];
            float2 o2;
            o2.x = PI_F / (1.f + __expf(-c0 * (0.1f / PI_F)));
            o2.y = 50.f * elu(c1 + 2.4f);
            *(float2*)(out + (size_t)trip * 2) = o2;
        }
    };

    const int step = gridDim.x * 4;
    int p = blockIdx.x * 4 + wid;
    auto clampP = [&](int x) { return x < NPAIRS ? x : NPAIRS - 1; };

    I3 iA, iB, jA, jB;
    loadIdx(clampP(p), iA, iB);
    bf16x8 fr[12];
    loadFrags(iA, iB, fr);
    loadIdx(clampP(p + step), jA, jB);

    while (p < NPAIRS) {
        bf16x8 zA[2], zB2[2];
        buildZ(fr, zA);
        buildZ(fr + 6, zB2);

        // fr is dead now: reload it in-place with the NEXT pair's gathers
        loadFrags(jA, jB, fr);
        loadIdx(clampP(p + 2 * step), jA, jB);

        f32x4 sA[4], sB[4], tA_[4], tB_[4];
        gemmDual(0, zA, zB2, sA, sB);      // skip: z @ Ws
        gemmDual(1, zA, zB2, tA_, tB_);    // main: z @ W1

        // a1 = elu(t1 + b1)
#pragma unroll
        for (int mt = 0; mt < 4; ++mt) {
            float4 bv = *(const float4*)&bC[0][mt * 16 + 4 * q];
#pragma unroll
            for (int r = 0; r < 4; ++r) {
                tA_[mt][r] = elu(tA_[mt][r] + ((const float*)&bv)[r]);
                tB_[mt][r] = elu(tB_[mt][r] + ((const float*)&bv)[r]);
            }
        }
        bf16x8 aA[2], aB[2];
        c2bDual(tA_, tB_, aA, aB);
        gemmDual(2, aA, aB, tA_, tB_);     // a1 @ W2

        // z2 = elu(skip + main + (bs+b2))
#pragma unroll
        for (int mt = 0; mt < 4; ++mt) {
            float4 bv = *(const float4*)&bC[1][mt * 16 + 4 * q];
#pragma unroll
            for (int r = 0; r < 4; ++r) {
                tA_[mt][r] = elu(sA[mt][r] + tA_[mt][r] + ((const float*)&bv)[r]);
                tB_[mt][r] = elu(sB[mt][r] + tB_[mt][r] + ((const float*)&bv)[r]);
            }
        }
        c2bDual(tA_, tB_, aA, aB);
        gemmDual(3, aA, aB, tA_, tB_);     // z2 @ W3

        epi(tA_, p * 32 + t);
        epi(tB_, p * 32 + 16 + t);

        p += step;
    }
}

extern "C" void kernel_launch(void* const* d_in, const int* in_sizes, int n_in,
                              void* d_out, int out_size, void* d_ws, size_t ws_size,
                              hipStream_t stream) {
    const float* h  = (const float*)d_in[0];
    const int* idxs = (const int*)d_in[1];
    const float* W0 = (const float*)d_in[2];
    const float* b0 = (const float*)d_in[3];
    const float* Ws = (const float*)d_in[4];
    const float* bs = (const float*)d_in[5];
    const float* W1 = (const float*)d_in[6];
    const float* b1 = (const float*)d_in[7];
    const float* W2 = (const float*)d_in[8];
    const float* b2 = (const float*)d_in[9];
    const float* W3 = (const float*)d_in[10];
    const float* b3 = (const float*)d_in[11];
    const float* W4 = (const float*)d_in[12];
    const float* b4 = (const float*)d_in[13];
    float* out = (float*)d_out;

    unsigned short* P    = (unsigned short*)d_ws;         // 200000*192 bf16 = 76.8 MB
    unsigned short* w0t2 = P + (size_t)N_NODES * 192;     // 49152 bf16

    prep_w0<<<192, 256, 0, stream>>>(W0, w0t2);
    stage1<<<512, 256, 0, stream>>>(h, w0t2, b0, P);
    stage2<<<512, 256, 0, stream>>>(P, idxs, Ws, bs, W1, b1, W2, b2, W3, b3, W4, b4, out);
}